// Round 1
// baseline (12978.947 us; speedup 1.0000x reference)
//
#include <hip/hip_runtime.h>
#include <math.h>

// Problem constants
constexpr int kH    = 1024;
constexpr int kT    = 2048;
constexpr int kIN   = 5;
constexpr int kOUT  = 9;

// Kernel geometry: 64 WGs x 512 threads. Each WG owns 16 h/c elements
// (j in [b*16, b*16+16)) and the 64 w_hh rows feeding them (4 gates x 16 j).
// w_hh held entirely in registers: 64 rows x 1024 cols / 512 thr = 128 f32/thr.
constexpr int kNWG   = 64;
constexpr int kBLOCK = 512;
constexpr int kJPW   = kH / kNWG;      // 16 j per WG
constexpr int kROWS  = 4 * kJPW;       // 64 rows per WG
constexpr int kWAVES = kBLOCK / 64;    // 8 waves
constexpr int kRPW   = kROWS / kWAVES; // 8 rows per wave
constexpr int kKC    = kH / 64;        // 16 cols per lane

__device__ __forceinline__ float sigmoidf_(float v) {
  return 1.0f / (1.0f + expf(-v));
}

__global__ __launch_bounds__(kBLOCK, 2) void lstm_persistent(
    const float* __restrict__ x,     // [T,1,IN]
    const float* __restrict__ w_ih,  // [4H,IN]
    const float* __restrict__ w_hh,  // [4H,H]
    const float* __restrict__ b_ih,  // [4H]
    const float* __restrict__ b_hh,  // [4H]
    const float* __restrict__ w_out, // [OUT,H]
    const float* __restrict__ b_out, // [OUT]
    float* __restrict__ out,         // [OUT]
    float* __restrict__ ws) {
  const int b    = blockIdx.x;
  const int tid  = threadIdx.x;
  const int w    = tid >> 6;
  const int lane = tid & 63;

  // Workspace layout (floats): hbuf0[1024], hbuf1[1024], slots[64 ints]
  float* hbuf0 = ws;
  float* hbuf1 = ws + kH;
  int*   slots = (int*)(ws + 2 * kH);

  __shared__ float h_lds[kH];
  __shared__ float g_lds[kROWS];
  __shared__ float c_lds[kJPW];
  __shared__ float wih_lds[kROWS][kIN];
  __shared__ float bias_lds[kROWS];

  // ---- one-time preload: w_ih slice + combined bias into LDS ----
  for (int r = tid; r < kROWS; r += kBLOCK) {
    const int gi  = r >> 4;         // gate index 0..3 ([i,f,g,o])
    const int jj  = r & 15;
    const int row = gi * kH + b * kJPW + jj;
#pragma unroll
    for (int k = 0; k < kIN; ++k) wih_lds[r][k] = w_ih[row * kIN + k];
    bias_lds[r] = b_ih[row] + b_hh[row];
  }
  if (tid < kJPW) c_lds[tid] = 0.0f;

  // ---- one-time preload: w_hh slice into registers ----
  // wave w owns rows r_idx in [w*8, w*8+8); lane owns cols lane + 64*k.
  float wreg[kRPW][kKC];
#pragma unroll
  for (int r = 0; r < kRPW; ++r) {
    const int r_idx = w * kRPW + r;
    const int gi    = r_idx >> 4;
    const int jj    = r_idx & 15;
    const int row   = gi * kH + b * kJPW + jj;
    const float* wr = w_hh + (size_t)row * kH + lane;
#pragma unroll
    for (int k = 0; k < kKC; ++k) wreg[r][k] = wr[k * 64];
  }
  __syncthreads();

  // ---- sequential recurrence ----
  for (int t = 0; t < kT; ++t) {
    // Gate: wait until every WG has published h_t (slot >= t).
    if (tid < kNWG) {
      while (__hip_atomic_load(&slots[tid], __ATOMIC_ACQUIRE,
                               __HIP_MEMORY_SCOPE_AGENT) < t) { }
    }
    __syncthreads();

    // Stage h_t into LDS (agent-scope loads: bypass stale L1/L2).
    const float* hsrc = (t & 1) ? hbuf1 : hbuf0;
#pragma unroll
    for (int i = 0; i < kH / kBLOCK; ++i) {
      const int idx = tid + i * kBLOCK;
      h_lds[idx] = __hip_atomic_load((const float*)(hsrc + idx),
                                     __ATOMIC_RELAXED, __HIP_MEMORY_SCOPE_AGENT);
    }
    __syncthreads();

    // matvec: 8 rows/wave, 16 cols/lane, all register-resident weights.
    float acc[kRPW];
#pragma unroll
    for (int r = 0; r < kRPW; ++r) acc[r] = 0.0f;
#pragma unroll
    for (int k = 0; k < kKC; ++k) {
      const float hv = h_lds[lane + 64 * k];
#pragma unroll
      for (int r = 0; r < kRPW; ++r) acc[r] = fmaf(wreg[r][k], hv, acc[r]);
    }
    // butterfly all-reduce each row across the wave
#pragma unroll
    for (int r = 0; r < kRPW; ++r) {
#pragma unroll
      for (int off = 32; off; off >>= 1) acc[r] += __shfl_xor(acc[r], off, 64);
    }
    // lane r takes row (w*8 + r); add input-gate contribution + bias
    float myv = 0.0f;
#pragma unroll
    for (int r = 0; r < kRPW; ++r) myv = (lane == r) ? acc[r] : myv;
    if (lane < kRPW) {
      const int r_idx = w * kRPW + lane;
      const float* xt = x + (size_t)t * kIN;
      float gx = bias_lds[r_idx];
#pragma unroll
      for (int k = 0; k < kIN; ++k) gx = fmaf(wih_lds[r_idx][k], xt[k], gx);
      g_lds[r_idx] = myv + gx;
    }
    __syncthreads();

    // gate combine + state update for this WG's 16 j's
    if (tid < kJPW) {
      const float gi_ = g_lds[tid];
      const float gf_ = g_lds[kJPW + tid];
      const float gg_ = g_lds[2 * kJPW + tid];
      const float go_ = g_lds[3 * kJPW + tid];
      const float ii = sigmoidf_(gi_);
      const float ff = sigmoidf_(gf_);
      const float gg = tanhf(gg_);
      const float oo = sigmoidf_(go_);
      const float c  = ff * c_lds[tid] + ii * gg;
      c_lds[tid] = c;
      const float h = oo * tanhf(c);
      float* hdst = ((t + 1) & 1) ? hbuf1 : hbuf0;
      __hip_atomic_store(hdst + b * kJPW + tid, h, __ATOMIC_RELEASE,
                         __HIP_MEMORY_SCOPE_AGENT);
    }
    __syncthreads();
    if (tid == 0) {
      __hip_atomic_store(&slots[b], t + 1, __ATOMIC_RELEASE,
                         __HIP_MEMORY_SCOPE_AGENT);
    }
  }

  // ---- epilogue: tanh -> 9x1024 matvec -> log_softmax, on WG0 wave0 ----
  if (b == 0) {
    if (tid < kNWG) {
      while (__hip_atomic_load(&slots[tid], __ATOMIC_ACQUIRE,
                               __HIP_MEMORY_SCOPE_AGENT) < kT) { }
    }
    __syncthreads();
    if (w == 0) {
      const float* hf = (kT & 1) ? hbuf1 : hbuf0;
      float z[kKC];
#pragma unroll
      for (int k = 0; k < kKC; ++k) {
        const float hv = __hip_atomic_load((const float*)(hf + lane + 64 * k),
                                           __ATOMIC_RELAXED,
                                           __HIP_MEMORY_SCOPE_AGENT);
        z[k] = tanhf(hv);
      }
      float logits[kOUT];
#pragma unroll
      for (int r = 0; r < kOUT; ++r) {
        float a = 0.0f;
#pragma unroll
        for (int k = 0; k < kKC; ++k)
          a = fmaf(w_out[(size_t)r * kH + lane + 64 * k], z[k], a);
#pragma unroll
        for (int off = 32; off; off >>= 1) a += __shfl_xor(a, off, 64);
        logits[r] = a + b_out[r];
      }
      if (lane == 0) {
        float m = logits[0];
#pragma unroll
        for (int r = 1; r < kOUT; ++r) m = fmaxf(m, logits[r]);
        float s = 0.0f;
#pragma unroll
        for (int r = 0; r < kOUT; ++r) s += expf(logits[r] - m);
        const float lse = m + logf(s);
#pragma unroll
        for (int r = 0; r < kOUT; ++r) out[r] = logits[r] - lse;
      }
    }
  }
}

extern "C" void kernel_launch(void* const* d_in, const int* in_sizes, int n_in,
                              void* d_out, int out_size, void* d_ws, size_t ws_size,
                              hipStream_t stream) {
  const float* x     = (const float*)d_in[0];
  const float* w_ih  = (const float*)d_in[1];
  const float* w_hh  = (const float*)d_in[2];
  const float* b_ih  = (const float*)d_in[3];
  const float* b_hh  = (const float*)d_in[4];
  const float* w_out = (const float*)d_in[5];
  const float* b_out = (const float*)d_in[6];
  float* out = (float*)d_out;
  float* ws  = (float*)d_ws;

  // Zero h double-buffer + slot counters each call (graph-replay safe:
  // hipMemsetAsync on the capture stream is legal; all sync state restarts).
  const size_t sync_bytes = (size_t)(2 * kH + kNWG) * sizeof(float);
  hipMemsetAsync(d_ws, 0, sync_bytes, stream);

  lstm_persistent<<<kNWG, kBLOCK, 0, stream>>>(x, w_ih, w_hh, b_ih, b_hh,
                                               w_out, b_out, out, ws);
}

// Round 2
// 6274.750 us; speedup vs baseline: 2.0684x; 2.0684x over previous
//
#include <hip/hip_runtime.h>
#include <math.h>

// LSTM H=1024, T=2048, IN=5, OUT=9, batch=1.
// Design: 64 persistent WGs x 512 threads. Wave w of WG b owns j0=b*16+2w and
// j0+1. w_hh held in registers/AGPRs (128 f32/thread). Cross-WG sync carrier:
// tagged 8B atoms (hi32 = step tag, lo32 = h bits) in a depth-4 ring in d_ws.
// Per step: wave0 polls tags for step t, stages h into LDS, raises LDS flag;
// waves 1-7 spin on the flag. Matvec partials reduce via in-wave
// reduce-scatter (row lane&7 lands on its lane), gates applied per-lane,
// quad-gather via shfl, lanes 0/4 publish the two new tagged h values.
// No __syncthreads inside the time loop.

constexpr int kH    = 1024;
constexpr int kT    = 2048;
constexpr int kIN   = 5;
constexpr int kOUT  = 9;
constexpr int kNWG  = 64;
constexpr int kBLOCK = 512;
constexpr int kKC   = kH / 64;   // 16 columns per lane

typedef unsigned int       u32;
typedef unsigned long long u64;

__device__ __forceinline__ float sigm_(float v) {
  return 1.0f / (1.0f + expf(-v));
}
__device__ __forceinline__ float tanh_(float v) {
  return 1.0f - 2.0f / (expf(2.0f * v) + 1.0f);
}

__global__ __launch_bounds__(kBLOCK, 2) void lstm_wavesync(
    const float* __restrict__ x,     // [T,1,IN]
    const float* __restrict__ w_ih,  // [4H,IN]
    const float* __restrict__ w_hh,  // [4H,H]
    const float* __restrict__ b_ih,  // [4H]
    const float* __restrict__ b_hh,  // [4H]
    const float* __restrict__ w_out, // [OUT,H]
    const float* __restrict__ b_out, // [OUT]
    float* __restrict__ out,         // [OUT]
    u64* __restrict__ ring) {        // ring[4][H] tagged h
  const int b    = blockIdx.x;
  const int tid  = threadIdx.x;
  const int w    = tid >> 6;
  const int lane = tid & 63;

  __shared__ float x_lds[kT * kIN];  // 40 KiB
  __shared__ float h_lds[kH];        // 4 KiB
  __shared__ int   hflag;

  // stage all x into LDS once (gx compute reads it off the critical path)
  for (int i = tid; i < kT * kIN; i += kBLOCK) x_lds[i] = x[i];
  if (tid == 0) hflag = 0;

  // wave w owns j0 = b*16 + 2w and j0+1. Row r in 0..7: jj = j0 + (r>>2),
  // gate = r&3 (order [i,f,g,o]); global w_hh row = gate*H + jj.
  const int j0 = b * 16 + 2 * w;
  float wreg[8][kKC];
#pragma unroll
  for (int r = 0; r < 8; ++r) {
    const int grow  = (r & 3) * kH + j0 + (r >> 2);
    const float* sp = w_hh + (size_t)grow * kH + lane;
#pragma unroll
    for (int k = 0; k < kKC; ++k) wreg[r][k] = sp[k * 64];
  }
  // per-lane input-weight row (row index = lane&7)
  const int rmy    = lane & 7;
  const int growmy = (rmy & 3) * kH + j0 + (rmy >> 2);
  float wihr[kIN];
#pragma unroll
  for (int k = 0; k < kIN; ++k) wihr[k] = w_ih[growmy * kIN + k];
  const float biasr = b_ih[growmy] + b_hh[growmy];

  float cst = 0.0f;  // cell state for this lane's quad's j
  __syncthreads();   // x_lds + hflag ready (only barrier in the kernel)

  for (int t = 0; t < kT; ++t) {
    // ---- gx for row (lane&7) at step t — before the wait, off crit path
    float gx = biasr;
#pragma unroll
    for (int k = 0; k < kIN; ++k) gx = fmaf(wihr[k], x_lds[t * kIN + k], gx);

    // ---- acquire h_t
    const u64* rsrc = ring + (size_t)(t & 3) * kH;
    float hv[kKC];
    if (w == 0) {
      u64 v[kKC];
      bool done = false;
      while (!done) {
        done = true;
#pragma unroll
        for (int k = 0; k < kKC; ++k)
          v[k] = __hip_atomic_load(rsrc + lane + 64 * k, __ATOMIC_RELAXED,
                                   __HIP_MEMORY_SCOPE_AGENT);
#pragma unroll
        for (int k = 0; k < kKC; ++k)
          done = done && ((u32)(v[k] >> 32) == (u32)t);
      }
#pragma unroll
      for (int k = 0; k < kKC; ++k) {
        hv[k] = __uint_as_float((u32)v[k]);
        h_lds[lane + 64 * k] = hv[k];
      }
      if (lane == 0)
        __hip_atomic_store(&hflag, t + 1, __ATOMIC_RELEASE,
                           __HIP_MEMORY_SCOPE_WORKGROUP);
    } else {
      while (__hip_atomic_load(&hflag, __ATOMIC_ACQUIRE,
                               __HIP_MEMORY_SCOPE_WORKGROUP) < t + 1) { }
#pragma unroll
      for (int k = 0; k < kKC; ++k) hv[k] = h_lds[lane + 64 * k];
    }

    // ---- matvec partials: 8 rows x 16 cols per lane
    float acc[8];
#pragma unroll
    for (int r = 0; r < 8; ++r) acc[r] = 0.0f;
#pragma unroll
    for (int k = 0; k < kKC; ++k) {
#pragma unroll
      for (int r = 0; r < 8; ++r) acc[r] = fmaf(wreg[r][k], hv[k], acc[r]);
    }

    // ---- reduce-scatter: total of row (lane&7) lands on this lane (10 shfl)
    const int b0 = lane & 1, b1 = (lane >> 1) & 1, b2 = (lane >> 2) & 1;
    float n0, n1, n2, n3, m0, m1, f;
    {
      float k0 = b0 ? acc[1] : acc[0], s0 = b0 ? acc[0] : acc[1];
      float k1 = b0 ? acc[3] : acc[2], s1 = b0 ? acc[2] : acc[3];
      float k2 = b0 ? acc[5] : acc[4], s2 = b0 ? acc[4] : acc[5];
      float k3 = b0 ? acc[7] : acc[6], s3 = b0 ? acc[6] : acc[7];
      n0 = k0 + __shfl_xor(s0, 1);
      n1 = k1 + __shfl_xor(s1, 1);
      n2 = k2 + __shfl_xor(s2, 1);
      n3 = k3 + __shfl_xor(s3, 1);
    }
    {
      float k0 = b1 ? n1 : n0, s0 = b1 ? n0 : n1;
      float k1 = b1 ? n3 : n2, s1 = b1 ? n2 : n3;
      m0 = k0 + __shfl_xor(s0, 2);
      m1 = k1 + __shfl_xor(s1, 2);
    }
    {
      float k0 = b2 ? m1 : m0, s0 = b2 ? m0 : m1;
      f = k0 + __shfl_xor(s0, 4);
    }
    f += __shfl_xor(f, 8);
    f += __shfl_xor(f, 16);
    f += __shfl_xor(f, 32);

    // ---- per-lane nonlinearity (gate = lane&3; [i,f,g,o], g -> tanh)
    const float gtot = f + gx;
    const int   gate = lane & 3;
    const float u    = (gate == 2) ? 2.0f * gtot : gtot;
    float n = sigm_(u);
    n = (gate == 2) ? (2.0f * n - 1.0f) : n;

    // ---- quad gather + state update (lanes of a quad compute identically)
    const int   qb = lane & ~3;
    const float ni = __shfl(n, qb + 0);
    const float nf = __shfl(n, qb + 1);
    const float ng = __shfl(n, qb + 2);
    const float no = __shfl(n, qb + 3);
    cst = nf * cst + ni * ng;
    const float hval = no * tanh_(cst);

    // ---- publish tagged h (lanes 0 and 4 -> j0, j0+1)
    if ((lane & 3) == 0 && lane < 8) {
      const int jj = j0 + (lane >> 2);
      const u64 pack = ((u64)(u32)(t + 1) << 32) | (u64)__float_as_uint(hval);
      __hip_atomic_store(ring + (size_t)((t + 1) & 3) * kH + jj, pack,
                         __ATOMIC_RELAXED, __HIP_MEMORY_SCOPE_AGENT);
    }
  }

  // ---- epilogue: tanh -> 9x1024 matvec -> log_softmax (WG0 wave0)
  if (b == 0 && w == 0) {
    const u64* rfin = ring + (size_t)(kT & 3) * kH;  // ring[0], tag kT
    u64 v[kKC];
    bool done = false;
    while (!done) {
      done = true;
#pragma unroll
      for (int k = 0; k < kKC; ++k)
        v[k] = __hip_atomic_load(rfin + lane + 64 * k, __ATOMIC_RELAXED,
                                 __HIP_MEMORY_SCOPE_AGENT);
#pragma unroll
      for (int k = 0; k < kKC; ++k)
        done = done && ((u32)(v[k] >> 32) == (u32)kT);
    }
    float z[kKC];
#pragma unroll
    for (int k = 0; k < kKC; ++k) z[k] = tanh_(__uint_as_float((u32)v[k]));
    float logits[kOUT];
#pragma unroll
    for (int r = 0; r < kOUT; ++r) {
      float a = 0.0f;
#pragma unroll
      for (int k = 0; k < kKC; ++k)
        a = fmaf(w_out[(size_t)r * kH + lane + 64 * k], z[k], a);
#pragma unroll
      for (int off = 32; off; off >>= 1) a += __shfl_xor(a, off);
      logits[r] = a + b_out[r];
    }
    if (lane == 0) {
      float m = logits[0];
#pragma unroll
      for (int r = 1; r < kOUT; ++r) m = fmaxf(m, logits[r]);
      float s = 0.0f;
#pragma unroll
      for (int r = 0; r < kOUT; ++r) s += expf(logits[r] - m);
      const float lse = m + logf(s);
#pragma unroll
      for (int r = 0; r < kOUT; ++r) out[r] = logits[r] - lse;
    }
  }
}

extern "C" void kernel_launch(void* const* d_in, const int* in_sizes, int n_in,
                              void* d_out, int out_size, void* d_ws, size_t ws_size,
                              hipStream_t stream) {
  const float* x     = (const float*)d_in[0];
  const float* w_ih  = (const float*)d_in[1];
  const float* w_hh  = (const float*)d_in[2];
  const float* b_ih  = (const float*)d_in[3];
  const float* b_hh  = (const float*)d_in[4];
  const float* w_out = (const float*)d_in[5];
  const float* b_out = (const float*)d_in[6];
  float* out = (float*)d_out;
  u64*   ring = (u64*)d_ws;

  // Zero the whole depth-4 ring each call: ring[0] must carry (tag=0, h=0);
  // slots 1-3 must not hold garbage that aliases a future tag. 32 KiB.
  hipMemsetAsync(d_ws, 0, (size_t)4 * kH * sizeof(u64), stream);

  lstm_wavesync<<<kNWG, kBLOCK, 0, stream>>>(x, w_ih, w_hh, b_ih, b_hh,
                                             w_out, b_out, out, ring);
}